// Round 3
// baseline (1678.752 us; speedup 1.0000x reference)
//
#include <hip/hip_runtime.h>
#include <hip/hip_bf16.h>
#include <stdint.h>

typedef __attribute__((ext_vector_type(8))) __bf16 bf16x8;
typedef __attribute__((ext_vector_type(4))) float f32x4;

#define BM 128
#define BN 128
#define BK 64

__global__ __launch_bounds__(256, 3)
void awq_gemm(const float* __restrict__ X,
              const int* __restrict__ QW,
              const int* __restrict__ QZ,
              const float* __restrict__ S,
              const float* __restrict__ Bi,
              float* __restrict__ Out,
              int M, int N, int K) {
    const int PQ = K >> 3;          // int32 per qweight row
    const int NG = K >> 7;          // groups per row
    const int ZS = (NG + 7) >> 3;   // int32 per qzeros row

    __shared__ __align__(16) __bf16 As[BM * BK];
    __shared__ __align__(16) __bf16 Bs[BN * BK];

    const int tid  = threadIdx.x;
    const int lane = tid & 63;
    const int wid  = tid >> 6;

    // XCD-aware block swizzle (nwg = 64*86 = 5504, %8==0 -> bijective)
    const int nwg = gridDim.x;
    int bid = blockIdx.x;
    if ((nwg & 7) == 0) {
        const int cpx = nwg >> 3;
        bid = (bid & 7) * cpx + (bid >> 3);
    }
    const int nbn  = N / BN;
    const int brow = (bid / nbn) * BM;
    const int bcol = (bid % nbn) * BN;

    const int wm = wid >> 1;   // wave row (0..1)
    const int wn = wid & 1;    // wave col (0..1)

    f32x4 acc[4][4];
#pragma unroll
    for (int i = 0; i < 4; ++i)
#pragma unroll
        for (int j = 0; j < 4; ++j)
            acc[i][j] = {0.f, 0.f, 0.f, 0.f};

    // A-staging geometry: idx = it*256 + tid; row = idx>>3, 8-elem chunk = idx&7
    int arow[4], acch[4];
#pragma unroll
    for (int it = 0; it < 4; ++it) {
        const int idx = it * 256 + tid;
        arow[it] = idx >> 3;
        acch[it] = idx & 7;
    }

    // B-staging: 2 threads per output row, each handles 4 int32 (32 K-values)
    const int rb    = tid >> 1;    // row in B tile (0..127)
    const int bhalf = tid & 1;     // which 32-wide K half
    const int og    = bcol + rb;
    const int* qwrow = QW + (size_t)og * PQ;
    const int* qzrow = QZ + (size_t)og * ZS;
    const float* srow = S + (size_t)og * NG;

    for (int kk = 0; kk < K; kk += BK) {
        // ---- load A (f32 source) into regs, convert to bf16 ----
        bf16x8 areg[4];
#pragma unroll
        for (int it = 0; it < 4; ++it) {
            const float* gx = X + (size_t)(brow + arow[it]) * K + kk + acch[it] * 8;
            const float4 x0 = *(const float4*)gx;
            const float4 x1 = *(const float4*)(gx + 4);
            areg[it][0] = (__bf16)x0.x; areg[it][1] = (__bf16)x0.y;
            areg[it][2] = (__bf16)x0.z; areg[it][3] = (__bf16)x0.w;
            areg[it][4] = (__bf16)x1.x; areg[it][5] = (__bf16)x1.y;
            areg[it][6] = (__bf16)x1.z; areg[it][7] = (__bf16)x1.w;
        }

        const int4 qv = *(const int4*)(qwrow + (kk >> 3) + bhalf * 4);

        // ---- dequant B: 4 int32 -> 32 bf16 in regs ----
        const int g  = kk >> 7;
        const int zq = (qzrow[g >> 3] >> ((g & 7) * 4)) & 15;
        const float sf = srow[g];
        const float zs = (float)zq * sf;
        const int vs[4] = {qv.x, qv.y, qv.z, qv.w};
        bf16x8 wregs[4];
#pragma unroll
        for (int w = 0; w < 4; ++w) {
            const int v = vs[w];
#pragma unroll
            for (int j = 0; j < 8; ++j) {
                const float q = (float)((v >> (4 * j)) & 15);
                wregs[w][j] = (__bf16)(q * sf - zs);
            }
        }

        // ---- LDS writes (prev iteration's compute done at loop-end barrier) ----
#pragma unroll
        for (int it = 0; it < 4; ++it)
            *((bf16x8*)(As + (size_t)arow[it] * BK + acch[it] * 8)) = areg[it];
#pragma unroll
        for (int w = 0; w < 4; ++w)
            *((bf16x8*)(Bs + (size_t)rb * BK + bhalf * 32 + w * 8)) = wregs[w];

        __syncthreads();

        // ---- compute: 2 k-subtiles x 4x4 frags ----
#pragma unroll
        for (int ks = 0; ks < 2; ++ks) {
            bf16x8 af[4], bfr[4];
#pragma unroll
            for (int mi = 0; mi < 4; ++mi)
                af[mi] = *((const bf16x8*)(As + (size_t)(wm * 64 + mi * 16 + (lane & 15)) * BK
                                           + ks * 32 + (lane >> 4) * 8));
#pragma unroll
            for (int ni = 0; ni < 4; ++ni)
                bfr[ni] = *((const bf16x8*)(Bs + (size_t)(wn * 64 + ni * 16 + (lane & 15)) * BK
                                            + ks * 32 + (lane >> 4) * 8));
#pragma unroll
            for (int mi = 0; mi < 4; ++mi)
#pragma unroll
                for (int ni = 0; ni < 4; ++ni)
                    acc[mi][ni] = __builtin_amdgcn_mfma_f32_16x16x32_bf16(
                        af[mi], bfr[ni], acc[mi][ni], 0, 0, 0);
        }
        __syncthreads();   // compute done before next-iter staging overwrites
    }

    // ---- epilogue: C frag layout col=lane&15, row=(lane>>4)*4+r; f32 out ----
    const int cr0 = brow + wm * 64;
    const int cc0 = bcol + wn * 64;
#pragma unroll
    for (int ni = 0; ni < 4; ++ni) {
        const int col = cc0 + ni * 16 + (lane & 15);
        const float bv = Bi[col];
#pragma unroll
        for (int mi = 0; mi < 4; ++mi) {
#pragma unroll
            for (int r = 0; r < 4; ++r) {
                const int row = cr0 + mi * 16 + (lane >> 4) * 4 + r;
                Out[(size_t)row * N + col] = acc[mi][ni][r] + bv;
            }
        }
    }
}

extern "C" void kernel_launch(void* const* d_in, const int* in_sizes, int n_in,
                              void* d_out, int out_size, void* d_ws, size_t ws_size,
                              hipStream_t stream) {
    const float* X  = (const float*)d_in[0];
    const int*   QW = (const int*)d_in[1];
    const int*   QZ = (const int*)d_in[2];
    const float* S  = (const float*)d_in[3];
    const float* Bi = (const float*)d_in[4];
    float*       Out = (float*)d_out;

    const int O = in_sizes[4];           // 11008
    const int K = in_sizes[1] / O * 8;   // 4096
    const int M = in_sizes[0] / K;       // 8192

    const int grid = (M / BM) * (O / BN);
    awq_gemm<<<grid, 256, 0, stream>>>(X, QW, QZ, S, Bi, Out, M, O, K);
}

// Round 4
// 985.192 us; speedup vs baseline: 1.7040x; 1.7040x over previous
//
#include <hip/hip_runtime.h>
#include <hip/hip_bf16.h>
#include <stdint.h>

typedef __attribute__((ext_vector_type(8))) __bf16 bf16x8;
typedef __attribute__((ext_vector_type(4))) float f32x4;

#define BM 128
#define BN 128
#define BK 64

__device__ inline void gload_lds16(const void* g, void* l) {
    __builtin_amdgcn_global_load_lds(
        (const __attribute__((address_space(1))) uint32_t*)g,
        (__attribute__((address_space(3))) uint32_t*)l, 16, 0, 0);
}

// ---------------- pass 1a: X f32 -> bf16 ----------------
__global__ __launch_bounds__(256)
void cvt_x(const float* __restrict__ X, __bf16* __restrict__ Xb, size_t n8) {
    for (size_t i = blockIdx.x * 256ull + threadIdx.x; i < n8; i += (size_t)gridDim.x * 256ull) {
        const float4 x0 = *(const float4*)(X + i * 8);
        const float4 x1 = *(const float4*)(X + i * 8 + 4);
        bf16x8 v;
        v[0] = (__bf16)x0.x; v[1] = (__bf16)x0.y; v[2] = (__bf16)x0.z; v[3] = (__bf16)x0.w;
        v[4] = (__bf16)x1.x; v[5] = (__bf16)x1.y; v[6] = (__bf16)x1.z; v[7] = (__bf16)x1.w;
        *((bf16x8*)(Xb + i * 8)) = v;
    }
}

// ---------------- pass 1b: dequant W -> bf16 [N][K] ----------------
// one block per output row; thread c handles 4 int32 = 32 weights at k0=c*32
__global__ __launch_bounds__(128)
void dequant_w(const int* __restrict__ QW, const int* __restrict__ QZ,
               const float* __restrict__ S, __bf16* __restrict__ W, int N, int K) {
    const int PQ = K >> 3, NG = K >> 7, ZS = (NG + 7) >> 3;
    const int o = blockIdx.x;
    const int c = threadIdx.x;            // 0..K/32-1
    const int k0 = c * 32;
    const int g = k0 >> 7;
    const int zq = (QZ[(size_t)o * ZS + (g >> 3)] >> ((g & 7) * 4)) & 15;
    const float sf = S[(size_t)o * NG + g];
    const float zs = (float)zq * sf;
    const int4 qv = *(const int4*)(QW + (size_t)o * PQ + c * 4);
    const int vs[4] = {qv.x, qv.y, qv.z, qv.w};
#pragma unroll
    for (int w = 0; w < 4; ++w) {
        const int v = vs[w];
        bf16x8 wv;
#pragma unroll
        for (int j = 0; j < 8; ++j) {
            const float q = (float)((v >> (4 * j)) & 15);
            wv[j] = (__bf16)(q * sf - zs);
        }
        *((bf16x8*)(W + (size_t)o * K + k0 + w * 8)) = wv;
    }
}

// ---------------- pass 2: bf16 GEMM (m97 structure) ----------------
__global__ __launch_bounds__(256, 3)
void gemm_bf16(const __bf16* __restrict__ A, const __bf16* __restrict__ B,
               const float* __restrict__ Bi, float* __restrict__ Out,
               int M, int N, int K) {
    __shared__ __align__(16) __bf16 As[BM * BK];
    __shared__ __align__(16) __bf16 Bs[BN * BK];

    const int tid  = threadIdx.x;
    const int lane = tid & 63;
    const int wid  = tid >> 6;

    const int nwg = gridDim.x;
    int bid = blockIdx.x;
    if ((nwg & 7) == 0) {
        const int cpx = nwg >> 3;
        bid = (bid & 7) * cpx + (bid >> 3);
    }
    const int nbn  = N / BN;
    const int brow = (bid / nbn) * BM;
    const int bcol = (bid % nbn) * BN;

    const int wm = wid >> 1;
    const int wn = wid & 1;

    f32x4 acc[4][4];
#pragma unroll
    for (int i = 0; i < 4; ++i)
#pragma unroll
        for (int j = 0; j < 4; ++j)
            acc[i][j] = {0.f, 0.f, 0.f, 0.f};

    for (int kk = 0; kk < K; kk += BK) {
        // stage A and B: idx = it*256+tid; row=idx>>3, 16B chunk=idx&7; linear LDS
#pragma unroll
        for (int it = 0; it < 4; ++it) {
            const int idx = it * 256 + tid;
            const int row = idx >> 3;
            const int cch = idx & 7;
            gload_lds16(A + (size_t)(brow + row) * K + kk + cch * 8,
                        (void*)(As + (size_t)(it * 256 + wid * 64) * 8));
            gload_lds16(B + (size_t)(bcol + row) * K + kk + cch * 8,
                        (void*)(Bs + (size_t)(it * 256 + wid * 64) * 8));
        }
        __syncthreads();   // drains vmcnt(0): async LDS loads complete

#pragma unroll
        for (int ks = 0; ks < 2; ++ks) {
            bf16x8 af[4], bfr[4];
#pragma unroll
            for (int mi = 0; mi < 4; ++mi)
                af[mi] = *((const bf16x8*)(As + (size_t)(wm * 64 + mi * 16 + (lane & 15)) * BK
                                           + ks * 32 + (lane >> 4) * 8));
#pragma unroll
            for (int ni = 0; ni < 4; ++ni)
                bfr[ni] = *((const bf16x8*)(Bs + (size_t)(wn * 64 + ni * 16 + (lane & 15)) * BK
                                            + ks * 32 + (lane >> 4) * 8));
#pragma unroll
            for (int mi = 0; mi < 4; ++mi)
#pragma unroll
                for (int ni = 0; ni < 4; ++ni)
                    acc[mi][ni] = __builtin_amdgcn_mfma_f32_16x16x32_bf16(
                        af[mi], bfr[ni], acc[mi][ni], 0, 0, 0);
        }
        __syncthreads();
    }

    const int cr0 = brow + wm * 64;
    const int cc0 = bcol + wn * 64;
#pragma unroll
    for (int ni = 0; ni < 4; ++ni) {
        const int col = cc0 + ni * 16 + (lane & 15);
        const float bv = Bi[col];
#pragma unroll
        for (int mi = 0; mi < 4; ++mi) {
#pragma unroll
            for (int r = 0; r < 4; ++r) {
                const int row = cr0 + mi * 16 + (lane >> 4) * 4 + r;
                Out[(size_t)row * N + col] = acc[mi][ni][r] + bv;
            }
        }
    }
}

// ---------------- fallback: fused kernel with XOR-swizzled LDS ----------------
__global__ __launch_bounds__(256, 3)
void awq_gemm_fused(const float* __restrict__ X,
                    const int* __restrict__ QW,
                    const int* __restrict__ QZ,
                    const float* __restrict__ S,
                    const float* __restrict__ Bi,
                    float* __restrict__ Out,
                    int M, int N, int K) {
    const int PQ = K >> 3, NG = K >> 7, ZS = (NG + 7) >> 3;

    __shared__ __align__(16) __bf16 As[BM * BK];
    __shared__ __align__(16) __bf16 Bs[BN * BK];

    const int tid  = threadIdx.x;
    const int lane = tid & 63;
    const int wid  = tid >> 6;

    const int nwg = gridDim.x;
    int bid = blockIdx.x;
    if ((nwg & 7) == 0) {
        const int cpx = nwg >> 3;
        bid = (bid & 7) * cpx + (bid >> 3);
    }
    const int nbn  = N / BN;
    const int brow = (bid / nbn) * BM;
    const int bcol = (bid % nbn) * BN;

    const int wm = wid >> 1;
    const int wn = wid & 1;

    f32x4 acc[4][4];
#pragma unroll
    for (int i = 0; i < 4; ++i)
#pragma unroll
        for (int j = 0; j < 4; ++j)
            acc[i][j] = {0.f, 0.f, 0.f, 0.f};

    int arow[4], acch[4];
#pragma unroll
    for (int it = 0; it < 4; ++it) {
        const int idx = it * 256 + tid;
        arow[it] = idx >> 3;
        acch[it] = idx & 7;
    }

    const int rb    = tid >> 1;
    const int bhalf = tid & 1;
    const int og    = bcol + rb;
    const int* qwrow = QW + (size_t)og * PQ;
    const int* qzrow = QZ + (size_t)og * ZS;
    const float* srow = S + (size_t)og * NG;

    for (int kk = 0; kk < K; kk += BK) {
        bf16x8 areg[4];
#pragma unroll
        for (int it = 0; it < 4; ++it) {
            const float* gx = X + (size_t)(brow + arow[it]) * K + kk + acch[it] * 8;
            const float4 x0 = *(const float4*)gx;
            const float4 x1 = *(const float4*)(gx + 4);
            areg[it][0] = (__bf16)x0.x; areg[it][1] = (__bf16)x0.y;
            areg[it][2] = (__bf16)x0.z; areg[it][3] = (__bf16)x0.w;
            areg[it][4] = (__bf16)x1.x; areg[it][5] = (__bf16)x1.y;
            areg[it][6] = (__bf16)x1.z; areg[it][7] = (__bf16)x1.w;
        }

        const int4 qv = *(const int4*)(qwrow + (kk >> 3) + bhalf * 4);
        const int g  = kk >> 7;
        const int zq = (qzrow[g >> 3] >> ((g & 7) * 4)) & 15;
        const float sf = srow[g];
        const float zs = (float)zq * sf;
        const int vs[4] = {qv.x, qv.y, qv.z, qv.w};
        bf16x8 wregs[4];
#pragma unroll
        for (int w = 0; w < 4; ++w) {
            const int v = vs[w];
#pragma unroll
            for (int j = 0; j < 8; ++j) {
                const float q = (float)((v >> (4 * j)) & 15);
                wregs[w][j] = (__bf16)(q * sf - zs);
            }
        }

        // swizzled LDS writes: chunk' = chunk ^ (row&7)
#pragma unroll
        for (int it = 0; it < 4; ++it) {
            const int cs = acch[it] ^ (arow[it] & 7);
            *((bf16x8*)(As + (size_t)arow[it] * BK + cs * 8)) = areg[it];
        }
#pragma unroll
        for (int w = 0; w < 4; ++w) {
            const int cs = (bhalf * 4 + w) ^ (rb & 7);
            *((bf16x8*)(Bs + (size_t)rb * BK + cs * 8)) = wregs[w];
        }

        __syncthreads();

#pragma unroll
        for (int ks = 0; ks < 2; ++ks) {
            bf16x8 af[4], bfr[4];
#pragma unroll
            for (int mi = 0; mi < 4; ++mi) {
                const int row = wm * 64 + mi * 16 + (lane & 15);
                const int cs  = (ks * 4 + (lane >> 4)) ^ (row & 7);
                af[mi] = *((const bf16x8*)(As + (size_t)row * BK + cs * 8));
            }
#pragma unroll
            for (int ni = 0; ni < 4; ++ni) {
                const int row = wn * 64 + ni * 16 + (lane & 15);
                const int cs  = (ks * 4 + (lane >> 4)) ^ (row & 7);
                bfr[ni] = *((const bf16x8*)(Bs + (size_t)row * BK + cs * 8));
            }
#pragma unroll
            for (int mi = 0; mi < 4; ++mi)
#pragma unroll
                for (int ni = 0; ni < 4; ++ni)
                    acc[mi][ni] = __builtin_amdgcn_mfma_f32_16x16x32_bf16(
                        af[mi], bfr[ni], acc[mi][ni], 0, 0, 0);
        }
        __syncthreads();
    }

    const int cr0 = brow + wm * 64;
    const int cc0 = bcol + wn * 64;
#pragma unroll
    for (int ni = 0; ni < 4; ++ni) {
        const int col = cc0 + ni * 16 + (lane & 15);
        const float bv = Bi[col];
#pragma unroll
        for (int mi = 0; mi < 4; ++mi) {
#pragma unroll
            for (int r = 0; r < 4; ++r) {
                const int row = cr0 + mi * 16 + (lane >> 4) * 4 + r;
                Out[(size_t)row * N + col] = acc[mi][ni][r] + bv;
            }
        }
    }
}

extern "C" void kernel_launch(void* const* d_in, const int* in_sizes, int n_in,
                              void* d_out, int out_size, void* d_ws, size_t ws_size,
                              hipStream_t stream) {
    const float* X  = (const float*)d_in[0];
    const int*   QW = (const int*)d_in[1];
    const int*   QZ = (const int*)d_in[2];
    const float* S  = (const float*)d_in[3];
    const float* Bi = (const float*)d_in[4];
    float*       Out = (float*)d_out;

    const int O = in_sizes[4];           // 11008
    const int K = in_sizes[1] / O * 8;   // 4096
    const int M = in_sizes[0] / K;       // 8192

    const size_t szX = (size_t)M * K * sizeof(__bf16);   // 64 MiB
    const size_t szW = (size_t)O * K * sizeof(__bf16);   // 86 MiB
    const int grid = (M / BM) * (O / BN);

    if (ws_size >= szX + szW) {
        __bf16* Xb = (__bf16*)d_ws;
        __bf16* Wb = (__bf16*)((char*)d_ws + szX);
        const size_t n8 = (size_t)M * K / 8;
        cvt_x<<<2048, 256, 0, stream>>>(X, Xb, n8);
        dequant_w<<<O, K / 32, 0, stream>>>(QW, QZ, S, Wb, O, K);
        gemm_bf16<<<grid, 256, 0, stream>>>(Xb, Wb, Bi, Out, M, O, K);
    } else {
        awq_gemm_fused<<<grid, 256, 0, stream>>>(X, QW, QZ, S, Bi, Out, M, O, K);
    }
}